// Round 5
// baseline (506.759 us; speedup 1.0000x reference)
//
#include <hip/hip_runtime.h>
#include <math.h>

// Problem constants: B=8, N=1024, C=256, KS=512, H=8, HD=64
// ws layout (float offsets): stats[32] | q fp32[8192*512] (tau[64*1024] after k3) |
//   k fp32[8192*512] | bf16 planes (ushort): QH|QL|KH|KL (4 x PLSZ) then
//   XH|XL (2 x 2097152) then WH|WL (2 x 262144).
#define S_STAT 0
#define S_Q    32
#define S_K    (32 + 4194304)
#define S_PL   (32 + 8388608)
#define PLSZ   4194304

typedef unsigned short ushort;
typedef unsigned int uint;
typedef __attribute__((ext_vector_type(8))) short short8;
typedef __attribute__((ext_vector_type(16))) float floatx16;
typedef __attribute__((ext_vector_type(2))) float f32x2;
typedef __attribute__((ext_vector_type(4))) float f32x4;   // clang vector: valid for __builtin_nontemporal_store

__device__ __forceinline__ float wave_sum(float v) {
#pragma unroll
    for (int m = 1; m < 64; m <<= 1) v += __shfl_xor(v, m);
    return v;
}

// round-to-nearest-even fp32 -> bf16
__device__ __forceinline__ ushort f2bf(float f) {
    uint u = __float_as_uint(f);
    uint r = (u + 0x7fffu + ((u >> 16) & 1u)) >> 16;
    return (ushort)r;
}

__global__ __launch_bounds__(64) void k0_zero(float* __restrict__ ws) {
    if (threadIdx.x < 32) ws[S_STAT + threadIdx.x] = 0.0f;
}

// k_pre: split x (blocks 0..2047), qw (2048..2175), kw (2176..2303) into
// bf16 hi/lo planes. Each thread: one float4 -> ushort4 hi + ushort4 lo.
__global__ __launch_bounds__(256) void k_pre(const float* __restrict__ x,
                                             const float* __restrict__ qw,
                                             const float* __restrict__ kw,
                                             float* __restrict__ ws) {
    ushort* base = (ushort*)(ws + S_PL) + 4 * PLSZ;
    ushort* XH = base;
    ushort* XL = XH + 2097152;
    ushort* WH = XL + 2097152;
    ushort* WL = WH + 262144;
    const int bid = blockIdx.x;
    const int tid = threadIdx.x;
    const float* __restrict__ src;
    ushort *dh, *dl;
    int idx4;
    if (bid < 2048)      { src = x;  dh = XH;           dl = XL;           idx4 = bid * 256 + tid; }
    else if (bid < 2176) { src = qw; dh = WH;           dl = WL;           idx4 = (bid - 2048) * 256 + tid; }
    else                 { src = kw; dh = WH + 131072;  dl = WL + 131072;  idx4 = (bid - 2176) * 256 + tid; }
    const float4 v = *(const float4*)(src + (size_t)idx4 * 4);
    ushort4 hv, lv;
    {
        hv.x = f2bf(v.x); lv.x = f2bf(v.x - __uint_as_float(((uint)hv.x) << 16));
        hv.y = f2bf(v.y); lv.y = f2bf(v.y - __uint_as_float(((uint)hv.y) << 16));
        hv.z = f2bf(v.z); lv.z = f2bf(v.z - __uint_as_float(((uint)hv.z) << 16));
        hv.w = f2bf(v.w); lv.w = f2bf(v.w - __uint_as_float(((uint)hv.w) << 16));
    }
    *(ushort4*)(dh + (size_t)idx4 * 4) = hv;
    *(ushort4*)(dl + (size_t)idx4 * 4) = lv;
}

// K1 (MFMA): [8192 x 256] x [256 x 1024] -> q (cols 0..511) / k (cols 512..1023),
// split-bf16 3-term. Block = 128x128 tile, 4 waves (wave w: rows w&1, cols w>>1).
__global__ __launch_bounds__(256, 2) void k1_mfma(float* __restrict__ ws) {
    const ushort* base = (const ushort*)(ws + S_PL) + 4 * PLSZ;
    const ushort* __restrict__ XH = base;
    const ushort* __restrict__ XL = XH + 2097152;
    const ushort* __restrict__ WH = XL + 2097152;
    const ushort* __restrict__ WL = WH + 262144;
    const int t = threadIdx.x;
    const int l = t & 63;
    const int w = t >> 6;
    const int rw = w & 1, cw = w >> 1;
    const int row0 = blockIdx.x * 128 + rw * 64;   // n base of this wave
    const int col0 = blockIdx.y * 128 + cw * 64;   // j base of this wave (one head)
    const int lane31 = l & 31;
    const int kb8 = (l >> 5) * 8;

    floatx16 acc[2][2] = {};
#pragma unroll 4
    for (int kc = 0; kc < 256; kc += 16) {
        short8 ah[2], al[2], bh[2], bl[2];
#pragma unroll
        for (int rt = 0; rt < 2; ++rt) {
            const size_t o = (size_t)(row0 + rt * 32 + lane31) * 256 + kc + kb8;
            ah[rt] = *(const short8*)(XH + o);
            al[rt] = *(const short8*)(XL + o);
        }
#pragma unroll
        for (int ct = 0; ct < 2; ++ct) {
            const size_t o = (size_t)(col0 + ct * 32 + lane31) * 256 + kc + kb8;
            bh[ct] = *(const short8*)(WH + o);
            bl[ct] = *(const short8*)(WL + o);
        }
#pragma unroll
        for (int rt = 0; rt < 2; ++rt)
#pragma unroll
            for (int ct = 0; ct < 2; ++ct) {
                acc[rt][ct] = __builtin_amdgcn_mfma_f32_32x32x16_bf16(ah[rt], bh[ct], acc[rt][ct], 0, 0, 0);
                acc[rt][ct] = __builtin_amdgcn_mfma_f32_32x32x16_bf16(al[rt], bh[ct], acc[rt][ct], 0, 0, 0);
                acc[rt][ct] = __builtin_amdgcn_mfma_f32_32x32x16_bf16(ah[rt], bl[ct], acc[rt][ct], 0, 0, 0);
            }
    }

    const bool is_q = (col0 < 512);
    float* __restrict__ outp = ws + (is_q ? S_Q : S_K);
    const int cbase = col0 & 511;
    const int rsub = 4 * (l >> 5);
    float s1 = 0.f, s2 = 0.f;
#pragma unroll
    for (int rt = 0; rt < 2; ++rt)
#pragma unroll
        for (int ct = 0; ct < 2; ++ct)
#pragma unroll
            for (int e = 0; e < 16; ++e) {
                const int r = row0 + rt * 32 + rsub + (e & 3) + 8 * (e >> 2);
                const int c = cbase + ct * 32 + lane31;
                const float v = acc[rt][ct][e];
                outp[(size_t)r * 512 + c] = v;
                s1 += v; s2 += v * v;
            }
    s1 = wave_sum(s1);
    s2 = wave_sum(s2);
    if (l == 0) {
        const int head = (cbase >> 6) & 7;
        const int sb = (is_q ? 0 : 16) + head;
        atomicAdd(ws + S_STAT + sb, s1);
        atomicAdd(ws + S_STAT + sb + 8, s2);
    }
}

// K3: BN(train) + L2-normalize per 64-vector, then split into bf16 hi/lo planes
// (K pre-scaled by 1/16), plain n-major layout P[bh][n][d].
__global__ __launch_bounds__(256) void k3_norm(const float* __restrict__ bnw,
                                               const float* __restrict__ bnb,
                                               float* __restrict__ ws) {
    const int t = threadIdx.x;
    const int w = t >> 6, l = t & 63;
    const int nb = blockIdx.x;
    const int bh = blockIdx.y;
    const int b = bh >> 3, h = bh & 7;
    const int z = blockIdx.z;
    const float* __restrict__ in = ws + (z ? S_K : S_Q);
    const float* st = ws + S_STAT + (z ? 16 : 0);
    ushort* __restrict__ PH = (ushort*)(ws + S_PL) + (z ? 2 * PLSZ : 0) + (size_t)bh * 65536;
    ushort* __restrict__ PL = PH + PLSZ;
    const float inv_m = 1.0f / 524288.0f;
    const float mean  = st[h] * inv_m;
    const float var   = st[8 + h] * inv_m - mean * mean;
    const float alpha = rsqrtf(var + 1e-5f) * bnw[h];
    const float beta  = bnb[h] - mean * alpha;
    const float scale = z ? 0.0625f : 1.0f;   // fold 1/sqrt(256) into K

#pragma unroll 1
    for (int i = 0; i < 16; ++i) {
        const int n = nb * 64 + w * 16 + i;
        float v = in[(size_t)(b * 1024 + n) * 512 + h * 64 + l];
        v = fmaf(v, alpha, beta);
        float ss = wave_sum(v * v);
        v = v / fmaxf(sqrtf(ss), 1e-12f) * scale;
        ushort h16 = f2bf(v);
        float hif = __uint_as_float(((uint)h16) << 16);
        ushort l16 = f2bf(v - hif);
        const int idx = n * 64 + l;           // plain layout
        PH[idx] = h16;
        PL[idx] = l16;
    }
}

// K4a: tau only. Same block/MFMA/pass structure as the old k4 (block = bh x 32-m
// tile, full n), secant + exact-support, but stores just tau[bh][m] (256 KB)
// instead of the 268 MB output. The score computation (term order, k-step
// order) is kept bit-identical to k4b's recompute so support decisions match.
__global__ __launch_bounds__(256, 2) void k4a_tau(float* __restrict__ ws) {
    __shared__ float part[4][4][32];
    const int t = threadIdx.x;
    const int l = t & 63;
    const int w = t >> 6;
    const int bid = blockIdx.x;
    const int bh = bid & 63;          // same-bh blocks share an XCD (bid%8) for L2 reuse
    const int mt = bid >> 6;          // 0..31
    const int m0 = mt * 32;
    const ushort* __restrict__ QH = (const ushort*)(ws + S_PL);
    const ushort* __restrict__ QL = QH + PLSZ;
    const ushort* __restrict__ KH = QH + 2 * PLSZ;
    const ushort* __restrict__ KL = QH + 3 * PLSZ;

    const int row = l & 31;
    const int kb8 = l >> 5;

    short8 kf[2][4];
#pragma unroll
    for (int ks = 0; ks < 4; ++ks) {
        const size_t off = (size_t)(bh * 1024 + m0 + row) * 64 + ks * 16 + kb8 * 8;
        kf[0][ks] = *(const short8*)(KH + off);
        kf[1][ks] = *(const short8*)(KL + off);
    }

    floatx16 acc[8] = {};

#pragma unroll
    for (int r = 0; r < 8; ++r) {
        const size_t qoff = (size_t)(bh * 1024 + w * 256 + r * 32 + row) * 64 + kb8 * 8;
#pragma unroll
        for (int ks = 0; ks < 4; ++ks) {
            short8 ah = *(const short8*)(QH + qoff + ks * 16);
            short8 al = *(const short8*)(QL + qoff + ks * 16);
            acc[r] = __builtin_amdgcn_mfma_f32_32x32x16_bf16(ah, kf[0][ks], acc[r], 0, 0, 0);
            acc[r] = __builtin_amdgcn_mfma_f32_32x32x16_bf16(al, kf[0][ks], acc[r], 0, 0, 0);
            acc[r] = __builtin_amdgcn_mfma_f32_32x32x16_bf16(ah, kf[1][ks], acc[r], 0, 0, 0);
        }
    }

    // ---- sparsemax tau per column m = m0 + (l&31) over n = 1024 ----
    const int col = row;

    // pass 0: column sum (packed)
    {
        f32x2 sv = {0.f, 0.f};
#pragma unroll
        for (int r = 0; r < 8; ++r)
#pragma unroll
            for (int p = 0; p < 8; ++p) {
                f32x2 z2 = { acc[r][2 * p], acc[r][2 * p + 1] };
                sv += z2;
            }
        float vsuml = sv.x + sv.y;
        vsuml += __shfl_xor(vsuml, 32);
        if (l < 32) part[2][w][col] = vsuml;
    }
    __syncthreads();
    const float vsum = part[2][0][col] + part[2][1][col]
                     + part[2][2][col] + part[2][3][col];

    float tcur = (vsum - 1.0f) * (1.0f / 1024.0f);   // tau0 <= tau*
    float tprev = tcur, sprev = 0.f;
#pragma unroll 1
    for (int it = 0; it < 6; ++it) {
        f32x2 s2v = {0.f, 0.f};
#pragma unroll
        for (int r = 0; r < 8; ++r) {
            f32x2 sr = {0.f, 0.f};
#pragma unroll
            for (int p = 0; p < 8; ++p) {
                f32x2 z2 = { acc[r][2 * p], acc[r][2 * p + 1] };
                f32x2 d = z2 - tcur;         // v_pk_add_f32
                d.x = fmaxf(d.x, 0.f);       // scalar v_max (no packed fp32 max)
                d.y = fmaxf(d.y, 0.f);
                sr += d;                     // v_pk_add_f32
            }
            s2v += sr;                       // 8 independent chains, tree-combined
        }
        float sl = s2v.x + s2v.y;
        sl += __shfl_xor(sl, 32);
        if (l < 32) part[it & 1][w][col] = sl;
        __syncthreads();   // double-buffered partials: one barrier per eval
        const float s = part[it & 1][0][col] + part[it & 1][1][col]
                      + part[it & 1][2][col] + part[it & 1][3][col];
        const float g = s - 1.0f;
        float step;
        if (it == 0) {
            step = g * (1.0f / 1024.0f);     // Newton with full-support slope
        } else {
            const float denom = sprev - s;   // >= 0 by monotonicity
            step = (denom > 1e-30f) ? g * (tcur - tprev) / denom : 0.f;
        }
        step = fmaxf(step, 0.f);             // keep tau <= tau* (monotone)
        tprev = tcur; sprev = s;
        tcur += step;
    }

    // exact-support pass: tau = (sum_{z>tcur} z - 1) / cnt
    float cntl = 0.f, ssml = 0.f;
#pragma unroll
    for (int r = 0; r < 8; ++r)
#pragma unroll
        for (int e = 0; e < 16; ++e) {
            const float zz = acc[r][e];
            if (zz > tcur) { cntl += 1.f; ssml += zz; }
        }
    cntl += __shfl_xor(cntl, 32);
    ssml += __shfl_xor(ssml, 32);
    if (l < 32) { part[2][w][col] = cntl; part[3][w][col] = ssml; }
    __syncthreads();
    const float cnt  = part[2][0][col] + part[2][1][col] + part[2][2][col] + part[2][3][col];
    const float ssum = part[3][0][col] + part[3][1][col] + part[3][2][col] + part[3][3][col];
    const float tau = (ssum - 1.0f) / cnt;

    // tau store: wave 0, lanes 0..31 (all waves hold identical tau)
    if (t < 32) ws[S_Q + bh * 1024 + m0 + t] = tau;
}

// K4b: write-locality pass. Block = (bh, 32-row n-tile). Recomputes the scores
// (bit-identical MFMA term/k order to k4a), applies relu(z - tau), stages each
// 32n x 512m chunk through LDS, and streams the output as 1-KB-contiguous
// float4 wave bursts (per n-row: 512 consecutive floats; rows adjacent).
// 2 rounds/block (head = 1024 m). Replaces the old 128-B scattered stores
// (~1.5 TB/s effective) with long runs.
__global__ __launch_bounds__(256, 2) void k4b_store(const float* __restrict__ ws,
                                                    float* __restrict__ out) {
    __shared__ float st[32][512];
    const int t = threadIdx.x;
    const int l = t & 63;
    const int w = t >> 6;
    const int bid = blockIdx.x;
    const int bh = bid & 63;          // same-bh blocks share an XCD slot for K-plane L2 reuse
    const int nt = bid >> 6;          // 0..31
    const int b = bh >> 3, h = bh & 7;
    const int n0 = nt * 32;
    const ushort* __restrict__ QH = (const ushort*)(ws + S_PL);
    const ushort* __restrict__ QL = QH + PLSZ;
    const ushort* __restrict__ KH = QH + 2 * PLSZ;
    const ushort* __restrict__ KL = QH + 3 * PLSZ;
    const float* __restrict__ tauBuf = ws + S_Q + bh * 1024;  // [m]

    const int row = l & 31;
    const int kb8 = l >> 5;

    // A-fragments (Q n-tile), held across both rounds
    short8 qf[2][4];
#pragma unroll
    for (int ks = 0; ks < 4; ++ks) {
        const size_t off = (size_t)(bh * 1024 + n0 + row) * 64 + ks * 16 + kb8 * 8;
        qf[0][ks] = *(const short8*)(QH + off);
        qf[1][ks] = *(const short8*)(QL + off);
    }

    float* __restrict__ obase = out + (size_t)b * 1024 * 8192 + h * 1024;

#pragma unroll 1
    for (int rnd = 0; rnd < 2; ++rnd) {
        const int mchunk = rnd * 512;            // within head

        floatx16 acc[4] = {};
#pragma unroll
        for (int mt = 0; mt < 4; ++mt) {
            const int ml = mchunk + w * 128 + mt * 32;   // in-head m base of this tile
#pragma unroll
            for (int ks = 0; ks < 4; ++ks) {
                const size_t off = (size_t)(bh * 1024 + ml + row) * 64 + ks * 16 + kb8 * 8;
                short8 bhf = *(const short8*)(KH + off);
                short8 blf = *(const short8*)(KL + off);
                acc[mt] = __builtin_amdgcn_mfma_f32_32x32x16_bf16(qf[0][ks], bhf, acc[mt], 0, 0, 0);
                acc[mt] = __builtin_amdgcn_mfma_f32_32x32x16_bf16(qf[1][ks], bhf, acc[mt], 0, 0, 0);
                acc[mt] = __builtin_amdgcn_mfma_f32_32x32x16_bf16(qf[0][ks], blf, acc[mt], 0, 0, 0);
            }
        }

        __syncthreads();   // previous round's LDS reads complete before overwrite
#pragma unroll
        for (int mt = 0; mt < 4; ++mt) {
            const int mloc = w * 128 + mt * 32 + row;      // within 512-chunk
            const float taum = tauBuf[mchunk + mloc];
#pragma unroll
            for (int e = 0; e < 16; ++e) {
                const int n = (e & 3) + 8 * (e >> 2) + 4 * kb8;
                st[n][mloc] = fmaxf(acc[mt][e] - taum, 0.f);
            }
        }
        __syncthreads();

        // store: wave w writes rows w*8..w*8+7; per row two 1-KB wave bursts
#pragma unroll
        for (int j = 0; j < 8; ++j) {
            const int n = w * 8 + j;
            float* __restrict__ orow = obase + (size_t)(n0 + n) * 8192 + mchunk;
#pragma unroll
            for (int i = 0; i < 2; ++i) {
                const int moff = i * 256 + l * 4;
                const f32x4 v = *(const f32x4*)&st[n][moff];
                __builtin_nontemporal_store(v, (f32x4*)(orow + moff));
            }
        }
    }
}

extern "C" void kernel_launch(void* const* d_in, const int* in_sizes, int n_in,
                              void* d_out, int out_size, void* d_ws, size_t ws_size,
                              hipStream_t stream) {
    (void)in_sizes; (void)n_in; (void)out_size; (void)ws_size;
    const float* x   = (const float*)d_in[0];
    const float* qw  = (const float*)d_in[1];
    const float* kw  = (const float*)d_in[2];
    const float* bnw = (const float*)d_in[3];
    const float* bnb = (const float*)d_in[4];
    float* ws  = (float*)d_ws;
    float* out = (float*)d_out;

    hipLaunchKernelGGL(k0_zero, dim3(1), dim3(64), 0, stream, ws);
    hipLaunchKernelGGL(k_pre, dim3(2304), dim3(256), 0, stream, x, qw, kw, ws);
    hipLaunchKernelGGL(k1_mfma, dim3(64, 8), dim3(256), 0, stream, ws);
    hipLaunchKernelGGL(k3_norm, dim3(16, 64, 2), dim3(256), 0, stream, bnw, bnb, ws);
    hipLaunchKernelGGL(k4a_tau, dim3(2048), dim3(256), 0, stream, ws);
    hipLaunchKernelGGL(k4b_store, dim3(2048), dim3(256), 0, stream, ws, out);
}

// Round 6
// 469.332 us; speedup vs baseline: 1.0797x; 1.0797x over previous
//
#include <hip/hip_runtime.h>
#include <math.h>

// Problem constants: B=8, N=1024, C=256, KS=512, H=8, HD=64
// ws layout (float offsets): stats[32] | q fp32[8192*512] | k fp32[8192*512] |
//   bf16 planes (ushort): QH|QL|KH|KL (4 x PLSZ)  then  XH|XL (2 x 2097152)
//   then WH|WL (2 x 262144; cols 0..511 = qw rows, 512..1023 = kw rows).
#define S_STAT 0
#define S_Q    32
#define S_K    (32 + 4194304)
#define S_PL   (32 + 8388608)
#define PLSZ   4194304

typedef unsigned short ushort;
typedef unsigned int uint;
typedef __attribute__((ext_vector_type(8))) short short8;
typedef __attribute__((ext_vector_type(16))) float floatx16;
typedef __attribute__((ext_vector_type(2))) float f32x2;

__device__ __forceinline__ float wave_sum(float v) {
#pragma unroll
    for (int m = 1; m < 64; m <<= 1) v += __shfl_xor(v, m);
    return v;
}

// round-to-nearest-even fp32 -> bf16
__device__ __forceinline__ ushort f2bf(float f) {
    uint u = __float_as_uint(f);
    uint r = (u + 0x7fffu + ((u >> 16) & 1u)) >> 16;
    return (ushort)r;
}

__global__ __launch_bounds__(64) void k0_zero(float* __restrict__ ws) {
    if (threadIdx.x < 32) ws[S_STAT + threadIdx.x] = 0.0f;
}

// k_pre: split x (blocks 0..2047), qw (2048..2175), kw (2176..2303) into
// bf16 hi/lo planes. Each thread: one float4 -> ushort4 hi + ushort4 lo.
__global__ __launch_bounds__(256) void k_pre(const float* __restrict__ x,
                                             const float* __restrict__ qw,
                                             const float* __restrict__ kw,
                                             float* __restrict__ ws) {
    ushort* base = (ushort*)(ws + S_PL) + 4 * PLSZ;
    ushort* XH = base;
    ushort* XL = XH + 2097152;
    ushort* WH = XL + 2097152;
    ushort* WL = WH + 262144;
    const int bid = blockIdx.x;
    const int tid = threadIdx.x;
    const float* __restrict__ src;
    ushort *dh, *dl;
    int idx4;
    if (bid < 2048)      { src = x;  dh = XH;           dl = XL;           idx4 = bid * 256 + tid; }
    else if (bid < 2176) { src = qw; dh = WH;           dl = WL;           idx4 = (bid - 2048) * 256 + tid; }
    else                 { src = kw; dh = WH + 131072;  dl = WL + 131072;  idx4 = (bid - 2176) * 256 + tid; }
    const float4 v = *(const float4*)(src + (size_t)idx4 * 4);
    ushort4 hv, lv;
    {
        hv.x = f2bf(v.x); lv.x = f2bf(v.x - __uint_as_float(((uint)hv.x) << 16));
        hv.y = f2bf(v.y); lv.y = f2bf(v.y - __uint_as_float(((uint)hv.y) << 16));
        hv.z = f2bf(v.z); lv.z = f2bf(v.z - __uint_as_float(((uint)hv.z) << 16));
        hv.w = f2bf(v.w); lv.w = f2bf(v.w - __uint_as_float(((uint)hv.w) << 16));
    }
    *(ushort4*)(dh + (size_t)idx4 * 4) = hv;
    *(ushort4*)(dl + (size_t)idx4 * 4) = lv;
}

// K1 (MFMA): [8192 x 256] x [256 x 1024] -> q (cols 0..511) / k (cols 512..1023),
// split-bf16 3-term. Block = 128x128 tile, 4 waves (wave w: rows w&1, cols w>>1).
__global__ __launch_bounds__(256, 2) void k1_mfma(float* __restrict__ ws) {
    const ushort* base = (const ushort*)(ws + S_PL) + 4 * PLSZ;
    const ushort* __restrict__ XH = base;
    const ushort* __restrict__ XL = XH + 2097152;
    const ushort* __restrict__ WH = XL + 2097152;
    const ushort* __restrict__ WL = WH + 262144;
    const int t = threadIdx.x;
    const int l = t & 63;
    const int w = t >> 6;
    const int rw = w & 1, cw = w >> 1;
    const int row0 = blockIdx.x * 128 + rw * 64;   // n base of this wave
    const int col0 = blockIdx.y * 128 + cw * 64;   // j base of this wave (one head)
    const int lane31 = l & 31;
    const int kb8 = (l >> 5) * 8;

    floatx16 acc[2][2] = {};
#pragma unroll 4
    for (int kc = 0; kc < 256; kc += 16) {
        short8 ah[2], al[2], bh[2], bl[2];
#pragma unroll
        for (int rt = 0; rt < 2; ++rt) {
            const size_t o = (size_t)(row0 + rt * 32 + lane31) * 256 + kc + kb8;
            ah[rt] = *(const short8*)(XH + o);
            al[rt] = *(const short8*)(XL + o);
        }
#pragma unroll
        for (int ct = 0; ct < 2; ++ct) {
            const size_t o = (size_t)(col0 + ct * 32 + lane31) * 256 + kc + kb8;
            bh[ct] = *(const short8*)(WH + o);
            bl[ct] = *(const short8*)(WL + o);
        }
#pragma unroll
        for (int rt = 0; rt < 2; ++rt)
#pragma unroll
            for (int ct = 0; ct < 2; ++ct) {
                acc[rt][ct] = __builtin_amdgcn_mfma_f32_32x32x16_bf16(ah[rt], bh[ct], acc[rt][ct], 0, 0, 0);
                acc[rt][ct] = __builtin_amdgcn_mfma_f32_32x32x16_bf16(al[rt], bh[ct], acc[rt][ct], 0, 0, 0);
                acc[rt][ct] = __builtin_amdgcn_mfma_f32_32x32x16_bf16(ah[rt], bl[ct], acc[rt][ct], 0, 0, 0);
            }
    }

    const bool is_q = (col0 < 512);
    float* __restrict__ outp = ws + (is_q ? S_Q : S_K);
    const int cbase = col0 & 511;
    const int rsub = 4 * (l >> 5);
    float s1 = 0.f, s2 = 0.f;
#pragma unroll
    for (int rt = 0; rt < 2; ++rt)
#pragma unroll
        for (int ct = 0; ct < 2; ++ct)
#pragma unroll
            for (int e = 0; e < 16; ++e) {
                const int r = row0 + rt * 32 + rsub + (e & 3) + 8 * (e >> 2);
                const int c = cbase + ct * 32 + lane31;
                const float v = acc[rt][ct][e];
                outp[(size_t)r * 512 + c] = v;
                s1 += v; s2 += v * v;
            }
    s1 = wave_sum(s1);
    s2 = wave_sum(s2);
    if (l == 0) {
        const int head = (cbase >> 6) & 7;
        const int sb = (is_q ? 0 : 16) + head;
        atomicAdd(ws + S_STAT + sb, s1);
        atomicAdd(ws + S_STAT + sb + 8, s2);
    }
}

// K3: BN(train) + L2-normalize per 64-vector, then split into bf16 hi/lo planes
// (K pre-scaled by 1/16), plain n-major layout P[bh][n][d].
__global__ __launch_bounds__(256) void k3_norm(const float* __restrict__ bnw,
                                               const float* __restrict__ bnb,
                                               float* __restrict__ ws) {
    const int t = threadIdx.x;
    const int w = t >> 6, l = t & 63;
    const int nb = blockIdx.x;
    const int bh = blockIdx.y;
    const int b = bh >> 3, h = bh & 7;
    const int z = blockIdx.z;
    const float* __restrict__ in = ws + (z ? S_K : S_Q);
    const float* st = ws + S_STAT + (z ? 16 : 0);
    ushort* __restrict__ PH = (ushort*)(ws + S_PL) + (z ? 2 * PLSZ : 0) + (size_t)bh * 65536;
    ushort* __restrict__ PL = PH + PLSZ;
    const float inv_m = 1.0f / 524288.0f;
    const float mean  = st[h] * inv_m;
    const float var   = st[8 + h] * inv_m - mean * mean;
    const float alpha = rsqrtf(var + 1e-5f) * bnw[h];
    const float beta  = bnb[h] - mean * alpha;
    const float scale = z ? 0.0625f : 1.0f;   // fold 1/sqrt(256) into K

#pragma unroll 1
    for (int i = 0; i < 16; ++i) {
        const int n = nb * 64 + w * 16 + i;
        float v = in[(size_t)(b * 1024 + n) * 512 + h * 64 + l];
        v = fmaf(v, alpha, beta);
        float ss = wave_sum(v * v);
        v = v / fmaxf(sqrtf(ss), 1e-12f) * scale;
        ushort h16 = f2bf(v);
        float hif = __uint_as_float(((uint)h16) << 16);
        ushort l16 = f2bf(v - hif);
        const int idx = n * 64 + l;           // plain layout
        PH[idx] = h16;
        PL[idx] = l16;
    }
}

// K4: single-kernel again (r5 split regressed: k4a+k4b ~ 238 us > 194 us).
// Occupancy lever: __launch_bounds__(256, 3) -> 3 blocks/CU (12 waves, was 8).
// Register budget 170/wave: acc = 128 AGPR (irreducible), so the K-fragment
// register cache is dropped and K frags reload per (r,ks) - they are
// L1-resident (8 KB/block, shared by all 4 waves x 8 r iterations).
// Sparsemax: sum pass -> 6 monotone-secant evals -> exact-support pass -> NT
// scalar stores.
__global__ __launch_bounds__(256, 3) void k4_attn(const float* __restrict__ ws,
                                                  float* __restrict__ out) {
    __shared__ float part[4][4][32];
    const int t = threadIdx.x;
    const int l = t & 63;
    const int w = t >> 6;
    const int bid = blockIdx.x;
    const int bh = bid & 63;          // same-bh blocks share an XCD (bid%8) for L2 reuse
    const int mt = bid >> 6;          // 0..31
    const int b = bh >> 3, h = bh & 7;
    const int m0 = mt * 32;
    const ushort* __restrict__ QH = (const ushort*)(ws + S_PL);
    const ushort* __restrict__ QL = QH + PLSZ;
    const ushort* __restrict__ KH = QH + 2 * PLSZ;
    const ushort* __restrict__ KL = QH + 3 * PLSZ;

    const int row = l & 31;
    const int kb8 = l >> 5;

    floatx16 acc[8] = {};

    const size_t koff = (size_t)(bh * 1024 + m0 + row) * 64 + kb8 * 8;
#pragma unroll
    for (int r = 0; r < 8; ++r) {
        const size_t qoff = (size_t)(bh * 1024 + w * 256 + r * 32 + row) * 64 + kb8 * 8;
#pragma unroll
        for (int ks = 0; ks < 4; ++ks) {
            short8 ah = *(const short8*)(QH + qoff + ks * 16);
            short8 al = *(const short8*)(QL + qoff + ks * 16);
            short8 kh = *(const short8*)(KH + koff + ks * 16);   // L1-hit reload
            short8 kl = *(const short8*)(KL + koff + ks * 16);
            acc[r] = __builtin_amdgcn_mfma_f32_32x32x16_bf16(ah, kh, acc[r], 0, 0, 0);
            acc[r] = __builtin_amdgcn_mfma_f32_32x32x16_bf16(al, kh, acc[r], 0, 0, 0);
            acc[r] = __builtin_amdgcn_mfma_f32_32x32x16_bf16(ah, kl, acc[r], 0, 0, 0);
        }
    }

    // ---- sparsemax per column m = m0 + (l&31) over n = 1024 ----
    const int col = row;

    // pass 0: column sum (packed)
    {
        f32x2 sv = {0.f, 0.f};
#pragma unroll
        for (int r = 0; r < 8; ++r)
#pragma unroll
            for (int p = 0; p < 8; ++p) {
                f32x2 z2 = { acc[r][2 * p], acc[r][2 * p + 1] };
                sv += z2;
            }
        float vsuml = sv.x + sv.y;
        vsuml += __shfl_xor(vsuml, 32);
        if (l < 32) part[2][w][col] = vsuml;
    }
    __syncthreads();
    const float vsum = part[2][0][col] + part[2][1][col]
                     + part[2][2][col] + part[2][3][col];

    float tcur = (vsum - 1.0f) * (1.0f / 1024.0f);   // tau0 <= tau*
    float tprev = tcur, sprev = 0.f;
#pragma unroll 1
    for (int it = 0; it < 6; ++it) {
        f32x2 s2v = {0.f, 0.f};
#pragma unroll
        for (int r = 0; r < 8; ++r) {
            f32x2 sr = {0.f, 0.f};
#pragma unroll
            for (int p = 0; p < 8; ++p) {
                f32x2 z2 = { acc[r][2 * p], acc[r][2 * p + 1] };
                f32x2 d = z2 - tcur;         // v_pk_add_f32
                d.x = fmaxf(d.x, 0.f);       // scalar v_max (no packed fp32 max)
                d.y = fmaxf(d.y, 0.f);
                sr += d;                     // v_pk_add_f32
            }
            s2v += sr;                       // 8 independent chains, tree-combined
        }
        float sl = s2v.x + s2v.y;
        sl += __shfl_xor(sl, 32);
        if (l < 32) part[it & 1][w][col] = sl;
        __syncthreads();   // double-buffered partials: one barrier per eval
        const float s = part[it & 1][0][col] + part[it & 1][1][col]
                      + part[it & 1][2][col] + part[it & 1][3][col];
        const float g = s - 1.0f;
        float step;
        if (it == 0) {
            step = g * (1.0f / 1024.0f);     // Newton with full-support slope
        } else {
            const float denom = sprev - s;   // >= 0 by monotonicity
            step = (denom > 1e-30f) ? g * (tcur - tprev) / denom : 0.f;
        }
        step = fmaxf(step, 0.f);             // keep tau <= tau* (monotone)
        tprev = tcur; sprev = s;
        tcur += step;
    }

    // exact-support pass: tau = (sum_{z>tcur} z - 1) / cnt
    float cntl = 0.f, ssml = 0.f;
#pragma unroll
    for (int r = 0; r < 8; ++r)
#pragma unroll
        for (int e = 0; e < 16; ++e) {
            const float zz = acc[r][e];
            if (zz > tcur) { cntl += 1.f; ssml += zz; }
        }
    cntl += __shfl_xor(cntl, 32);
    ssml += __shfl_xor(ssml, 32);
    if (l < 32) { part[2][w][col] = cntl; part[3][w][col] = ssml; }
    __syncthreads();
    const float cnt  = part[2][0][col] + part[2][1][col] + part[2][2][col] + part[2][3][col];
    const float ssum = part[3][0][col] + part[3][1][col] + part[3][2][col] + part[3][3][col];
    const float tau = (ssum - 1.0f) / cnt;

    float* __restrict__ ob = out + (size_t)b * 1024 * 8192 + h * 1024 + m0 + col;
    const int nbase = w * 256 + 4 * kb8;
#pragma unroll
    for (int r = 0; r < 8; ++r)
#pragma unroll
        for (int e = 0; e < 16; ++e) {
            const int n = nbase + r * 32 + (e & 3) + 8 * (e >> 2);
            __builtin_nontemporal_store(fmaxf(acc[r][e] - tau, 0.f),
                                        ob + (size_t)n * 8192);
        }
}

extern "C" void kernel_launch(void* const* d_in, const int* in_sizes, int n_in,
                              void* d_out, int out_size, void* d_ws, size_t ws_size,
                              hipStream_t stream) {
    (void)in_sizes; (void)n_in; (void)out_size; (void)ws_size;
    const float* x   = (const float*)d_in[0];
    const float* qw  = (const float*)d_in[1];
    const float* kw  = (const float*)d_in[2];
    const float* bnw = (const float*)d_in[3];
    const float* bnb = (const float*)d_in[4];
    float* ws  = (float*)d_ws;
    float* out = (float*)d_out;

    hipLaunchKernelGGL(k0_zero, dim3(1), dim3(64), 0, stream, ws);
    hipLaunchKernelGGL(k_pre, dim3(2304), dim3(256), 0, stream, x, qw, kw, ws);
    hipLaunchKernelGGL(k1_mfma, dim3(64, 8), dim3(256), 0, stream, ws);
    hipLaunchKernelGGL(k3_norm, dim3(16, 64, 2), dim3(256), 0, stream, bnw, bnb, ws);
    hipLaunchKernelGGL(k4_attn, dim3(2048), dim3(256), 0, stream, ws, out);
}

// Round 7
// 442.827 us; speedup vs baseline: 1.1444x; 1.0599x over previous
//
#include <hip/hip_runtime.h>
#include <math.h>

// Problem constants: B=8, N=1024, C=256, KS=512, H=8, HD=64
// ws layout (float offsets): stats[32] | q fp32[8192*512] | k fp32[8192*512] |
//   bf16 planes (ushort): QH|QL|KH|KL (4 x PLSZ)  then  XH|XL (2 x 2097152)
//   then WH|WL (2 x 262144; cols 0..511 = qw rows, 512..1023 = kw rows).
#define S_STAT 0
#define S_Q    32
#define S_K    (32 + 4194304)
#define S_PL   (32 + 8388608)
#define PLSZ   4194304

typedef unsigned short ushort;
typedef unsigned int uint;
typedef __attribute__((ext_vector_type(8))) short short8;
typedef __attribute__((ext_vector_type(16))) float floatx16;
typedef __attribute__((ext_vector_type(2))) float f32x2;

__device__ __forceinline__ float wave_sum(float v) {
#pragma unroll
    for (int m = 1; m < 64; m <<= 1) v += __shfl_xor(v, m);
    return v;
}

// round-to-nearest-even fp32 -> bf16
__device__ __forceinline__ ushort f2bf(float f) {
    uint u = __float_as_uint(f);
    uint r = (u + 0x7fffu + ((u >> 16) & 1u)) >> 16;
    return (ushort)r;
}

__global__ __launch_bounds__(64) void k0_zero(float* __restrict__ ws) {
    if (threadIdx.x < 32) ws[S_STAT + threadIdx.x] = 0.0f;
}

// k_pre: split x (blocks 0..2047), qw (2048..2175), kw (2176..2303) into
// bf16 hi/lo planes. Each thread: one float4 -> ushort4 hi + ushort4 lo.
__global__ __launch_bounds__(256) void k_pre(const float* __restrict__ x,
                                             const float* __restrict__ qw,
                                             const float* __restrict__ kw,
                                             float* __restrict__ ws) {
    ushort* base = (ushort*)(ws + S_PL) + 4 * PLSZ;
    ushort* XH = base;
    ushort* XL = XH + 2097152;
    ushort* WH = XL + 2097152;
    ushort* WL = WH + 262144;
    const int bid = blockIdx.x;
    const int tid = threadIdx.x;
    const float* __restrict__ src;
    ushort *dh, *dl;
    int idx4;
    if (bid < 2048)      { src = x;  dh = XH;           dl = XL;           idx4 = bid * 256 + tid; }
    else if (bid < 2176) { src = qw; dh = WH;           dl = WL;           idx4 = (bid - 2048) * 256 + tid; }
    else                 { src = kw; dh = WH + 131072;  dl = WL + 131072;  idx4 = (bid - 2176) * 256 + tid; }
    const float4 v = *(const float4*)(src + (size_t)idx4 * 4);
    ushort4 hv, lv;
    {
        hv.x = f2bf(v.x); lv.x = f2bf(v.x - __uint_as_float(((uint)hv.x) << 16));
        hv.y = f2bf(v.y); lv.y = f2bf(v.y - __uint_as_float(((uint)hv.y) << 16));
        hv.z = f2bf(v.z); lv.z = f2bf(v.z - __uint_as_float(((uint)hv.z) << 16));
        hv.w = f2bf(v.w); lv.w = f2bf(v.w - __uint_as_float(((uint)hv.w) << 16));
    }
    *(ushort4*)(dh + (size_t)idx4 * 4) = hv;
    *(ushort4*)(dl + (size_t)idx4 * 4) = lv;
}

// K1 (MFMA): [8192 x 256] x [256 x 1024] -> q (cols 0..511) / k (cols 512..1023),
// split-bf16 3-term. Block = 128x128 tile, 4 waves (wave w: rows w&1, cols w>>1).
__global__ __launch_bounds__(256, 2) void k1_mfma(float* __restrict__ ws) {
    const ushort* base = (const ushort*)(ws + S_PL) + 4 * PLSZ;
    const ushort* __restrict__ XH = base;
    const ushort* __restrict__ XL = XH + 2097152;
    const ushort* __restrict__ WH = XL + 2097152;
    const ushort* __restrict__ WL = WH + 262144;
    const int t = threadIdx.x;
    const int l = t & 63;
    const int w = t >> 6;
    const int rw = w & 1, cw = w >> 1;
    const int row0 = blockIdx.x * 128 + rw * 64;   // n base of this wave
    const int col0 = blockIdx.y * 128 + cw * 64;   // j base of this wave (one head)
    const int lane31 = l & 31;
    const int kb8 = (l >> 5) * 8;

    floatx16 acc[2][2] = {};
#pragma unroll 4
    for (int kc = 0; kc < 256; kc += 16) {
        short8 ah[2], al[2], bh[2], bl[2];
#pragma unroll
        for (int rt = 0; rt < 2; ++rt) {
            const size_t o = (size_t)(row0 + rt * 32 + lane31) * 256 + kc + kb8;
            ah[rt] = *(const short8*)(XH + o);
            al[rt] = *(const short8*)(XL + o);
        }
#pragma unroll
        for (int ct = 0; ct < 2; ++ct) {
            const size_t o = (size_t)(col0 + ct * 32 + lane31) * 256 + kc + kb8;
            bh[ct] = *(const short8*)(WH + o);
            bl[ct] = *(const short8*)(WL + o);
        }
#pragma unroll
        for (int rt = 0; rt < 2; ++rt)
#pragma unroll
            for (int ct = 0; ct < 2; ++ct) {
                acc[rt][ct] = __builtin_amdgcn_mfma_f32_32x32x16_bf16(ah[rt], bh[ct], acc[rt][ct], 0, 0, 0);
                acc[rt][ct] = __builtin_amdgcn_mfma_f32_32x32x16_bf16(al[rt], bh[ct], acc[rt][ct], 0, 0, 0);
                acc[rt][ct] = __builtin_amdgcn_mfma_f32_32x32x16_bf16(ah[rt], bl[ct], acc[rt][ct], 0, 0, 0);
            }
    }

    const bool is_q = (col0 < 512);
    float* __restrict__ outp = ws + (is_q ? S_Q : S_K);
    const int cbase = col0 & 511;
    const int rsub = 4 * (l >> 5);
    float s1 = 0.f, s2 = 0.f;
#pragma unroll
    for (int rt = 0; rt < 2; ++rt)
#pragma unroll
        for (int ct = 0; ct < 2; ++ct)
#pragma unroll
            for (int e = 0; e < 16; ++e) {
                const int r = row0 + rt * 32 + rsub + (e & 3) + 8 * (e >> 2);
                const int c = cbase + ct * 32 + lane31;
                const float v = acc[rt][ct][e];
                outp[(size_t)r * 512 + c] = v;
                s1 += v; s2 += v * v;
            }
    s1 = wave_sum(s1);
    s2 = wave_sum(s2);
    if (l == 0) {
        const int head = (cbase >> 6) & 7;
        const int sb = (is_q ? 0 : 16) + head;
        atomicAdd(ws + S_STAT + sb, s1);
        atomicAdd(ws + S_STAT + sb + 8, s2);
    }
}

// K3: BN(train) + L2-normalize per 64-vector, then split into bf16 hi/lo planes
// (K pre-scaled by 1/16), plain n-major layout P[bh][n][d].
__global__ __launch_bounds__(256) void k3_norm(const float* __restrict__ bnw,
                                               const float* __restrict__ bnb,
                                               float* __restrict__ ws) {
    const int t = threadIdx.x;
    const int w = t >> 6, l = t & 63;
    const int nb = blockIdx.x;
    const int bh = blockIdx.y;
    const int b = bh >> 3, h = bh & 7;
    const int z = blockIdx.z;
    const float* __restrict__ in = ws + (z ? S_K : S_Q);
    const float* st = ws + S_STAT + (z ? 16 : 0);
    ushort* __restrict__ PH = (ushort*)(ws + S_PL) + (z ? 2 * PLSZ : 0) + (size_t)bh * 65536;
    ushort* __restrict__ PL = PH + PLSZ;
    const float inv_m = 1.0f / 524288.0f;
    const float mean  = st[h] * inv_m;
    const float var   = st[8 + h] * inv_m - mean * mean;
    const float alpha = rsqrtf(var + 1e-5f) * bnw[h];
    const float beta  = bnb[h] - mean * alpha;
    const float scale = z ? 0.0625f : 1.0f;   // fold 1/sqrt(256) into K

#pragma unroll 1
    for (int i = 0; i < 16; ++i) {
        const int n = nb * 64 + w * 16 + i;
        float v = in[(size_t)(b * 1024 + n) * 512 + h * 64 + l];
        v = fmaf(v, alpha, beta);
        float ss = wave_sum(v * v);
        v = v / fmaxf(sqrtf(ss), 1e-12f) * scale;
        ushort h16 = f2bf(v);
        float hif = __uint_as_float(((uint)h16) << 16);
        ushort l16 = f2bf(v - hif);
        const int idx = n * 64 + l;           // plain layout
        PH[idx] = h16;
        PL[idx] = l16;
    }
}

// K4: write-locality via block mapping. bid = bh*32 + j (bh now SLOW): the 32
// sibling blocks of one bh-plane are co-resident and together cover all 1024 m
// of each output row. m0 = (j&7)*128 + (j>>3)*32: the 4 siblings landing on
// the same XCD (bid%8 round-robin) own a CONTIGUOUS 512-B m-strip per row, so
// their dirty lines cluster in that XCD's L2 (~0.5 MB/bh-group/XCD) and evict
// as adjacent-line groups instead of isolated 128-B lines at 32-KB stride.
// Stores are plain (not NT) so L2 aggregation can happen.
// Sparsemax: sum pass -> 6 monotone-secant evals -> exact-support pass.
__global__ __launch_bounds__(256, 3) void k4_attn(const float* __restrict__ ws,
                                                  float* __restrict__ out) {
    __shared__ float part[4][4][32];
    const int t = threadIdx.x;
    const int l = t & 63;
    const int w = t >> 6;
    const int bid = blockIdx.x;
    const int bh = bid >> 5;                    // 0..63 (slow)
    const int j  = bid & 31;                    // 0..31 (fast, co-resident siblings)
    const int m0 = ((j & 7) << 7) + ((j >> 3) << 5);  // XCD-contiguous m strips
    const int b = bh >> 3, h = bh & 7;
    const ushort* __restrict__ QH = (const ushort*)(ws + S_PL);
    const ushort* __restrict__ QL = QH + PLSZ;
    const ushort* __restrict__ KH = QH + 2 * PLSZ;
    const ushort* __restrict__ KL = QH + 3 * PLSZ;

    const int row = l & 31;
    const int kb8 = l >> 5;

    floatx16 acc[8] = {};

    const size_t koff = (size_t)(bh * 1024 + m0 + row) * 64 + kb8 * 8;
#pragma unroll
    for (int r = 0; r < 8; ++r) {
        const size_t qoff = (size_t)(bh * 1024 + w * 256 + r * 32 + row) * 64 + kb8 * 8;
#pragma unroll
        for (int ks = 0; ks < 4; ++ks) {
            short8 ah = *(const short8*)(QH + qoff + ks * 16);
            short8 al = *(const short8*)(QL + qoff + ks * 16);
            short8 kh = *(const short8*)(KH + koff + ks * 16);   // L1-hit reload
            short8 kl = *(const short8*)(KL + koff + ks * 16);
            acc[r] = __builtin_amdgcn_mfma_f32_32x32x16_bf16(ah, kh, acc[r], 0, 0, 0);
            acc[r] = __builtin_amdgcn_mfma_f32_32x32x16_bf16(al, kh, acc[r], 0, 0, 0);
            acc[r] = __builtin_amdgcn_mfma_f32_32x32x16_bf16(ah, kl, acc[r], 0, 0, 0);
        }
    }

    // ---- sparsemax per column m = m0 + (l&31) over n = 1024 ----
    const int col = row;

    // pass 0: column sum (packed)
    {
        f32x2 sv = {0.f, 0.f};
#pragma unroll
        for (int r = 0; r < 8; ++r)
#pragma unroll
            for (int p = 0; p < 8; ++p) {
                f32x2 z2 = { acc[r][2 * p], acc[r][2 * p + 1] };
                sv += z2;
            }
        float vsuml = sv.x + sv.y;
        vsuml += __shfl_xor(vsuml, 32);
        if (l < 32) part[2][w][col] = vsuml;
    }
    __syncthreads();
    const float vsum = part[2][0][col] + part[2][1][col]
                     + part[2][2][col] + part[2][3][col];

    float tcur = (vsum - 1.0f) * (1.0f / 1024.0f);   // tau0 <= tau*
    float tprev = tcur, sprev = 0.f;
#pragma unroll 1
    for (int it = 0; it < 6; ++it) {
        f32x2 s2v = {0.f, 0.f};
#pragma unroll
        for (int r = 0; r < 8; ++r) {
            f32x2 sr = {0.f, 0.f};
#pragma unroll
            for (int p = 0; p < 8; ++p) {
                f32x2 z2 = { acc[r][2 * p], acc[r][2 * p + 1] };
                f32x2 d = z2 - tcur;         // v_pk_add_f32
                d.x = fmaxf(d.x, 0.f);       // scalar v_max (no packed fp32 max)
                d.y = fmaxf(d.y, 0.f);
                sr += d;                     // v_pk_add_f32
            }
            s2v += sr;                       // 8 independent chains, tree-combined
        }
        float sl = s2v.x + s2v.y;
        sl += __shfl_xor(sl, 32);
        if (l < 32) part[it & 1][w][col] = sl;
        __syncthreads();   // double-buffered partials: one barrier per eval
        const float s = part[it & 1][0][col] + part[it & 1][1][col]
                      + part[it & 1][2][col] + part[it & 1][3][col];
        const float g = s - 1.0f;
        float step;
        if (it == 0) {
            step = g * (1.0f / 1024.0f);     // Newton with full-support slope
        } else {
            const float denom = sprev - s;   // >= 0 by monotonicity
            step = (denom > 1e-30f) ? g * (tcur - tprev) / denom : 0.f;
        }
        step = fmaxf(step, 0.f);             // keep tau <= tau* (monotone)
        tprev = tcur; sprev = s;
        tcur += step;
    }

    // exact-support pass: tau = (sum_{z>tcur} z - 1) / cnt
    float cntl = 0.f, ssml = 0.f;
#pragma unroll
    for (int r = 0; r < 8; ++r)
#pragma unroll
        for (int e = 0; e < 16; ++e) {
            const float zz = acc[r][e];
            if (zz > tcur) { cntl += 1.f; ssml += zz; }
        }
    cntl += __shfl_xor(cntl, 32);
    ssml += __shfl_xor(ssml, 32);
    if (l < 32) { part[2][w][col] = cntl; part[3][w][col] = ssml; }
    __syncthreads();
    const float cnt  = part[2][0][col] + part[2][1][col] + part[2][2][col] + part[2][3][col];
    const float ssum = part[3][0][col] + part[3][1][col] + part[3][2][col] + part[3][3][col];
    const float tau = (ssum - 1.0f) / cnt;

    float* __restrict__ ob = out + (size_t)b * 1024 * 8192 + h * 1024 + m0 + col;
    const int nbase = w * 256 + 4 * kb8;
#pragma unroll
    for (int r = 0; r < 8; ++r)
#pragma unroll
        for (int e = 0; e < 16; ++e) {
            const int n = nbase + r * 32 + (e & 3) + 8 * (e >> 2);
            ob[(size_t)n * 8192] = fmaxf(acc[r][e] - tau, 0.f);
        }
}

extern "C" void kernel_launch(void* const* d_in, const int* in_sizes, int n_in,
                              void* d_out, int out_size, void* d_ws, size_t ws_size,
                              hipStream_t stream) {
    (void)in_sizes; (void)n_in; (void)out_size; (void)ws_size;
    const float* x   = (const float*)d_in[0];
    const float* qw  = (const float*)d_in[1];
    const float* kw  = (const float*)d_in[2];
    const float* bnw = (const float*)d_in[3];
    const float* bnb = (const float*)d_in[4];
    float* ws  = (float*)d_ws;
    float* out = (float*)d_out;

    hipLaunchKernelGGL(k0_zero, dim3(1), dim3(64), 0, stream, ws);
    hipLaunchKernelGGL(k_pre, dim3(2304), dim3(256), 0, stream, x, qw, kw, ws);
    hipLaunchKernelGGL(k1_mfma, dim3(64, 8), dim3(256), 0, stream, ws);
    hipLaunchKernelGGL(k3_norm, dim3(16, 64, 2), dim3(256), 0, stream, bnw, bnb, ws);
    hipLaunchKernelGGL(k4_attn, dim3(2048), dim3(256), 0, stream, ws, out);
}

// Round 8
// 439.696 us; speedup vs baseline: 1.1525x; 1.0071x over previous
//
#include <hip/hip_runtime.h>
#include <math.h>

// Problem constants: B=8, N=1024, C=256, KS=512, H=8, HD=64
// ws layout (float offsets): stats[32] | q fp32[8192*512] | k fp32[8192*512] |
//   bf16 planes (ushort): QH|QL|KH|KL (4 x PLSZ)  then  XH|XL (2 x 2097152)
//   then WH|WL (2 x 262144; cols 0..511 = qw rows, 512..1023 = kw rows).
#define S_STAT 0
#define S_Q    32
#define S_K    (32 + 4194304)
#define S_PL   (32 + 8388608)
#define PLSZ   4194304

typedef unsigned short ushort;
typedef unsigned int uint;
typedef __attribute__((ext_vector_type(8))) short short8;
typedef __attribute__((ext_vector_type(16))) float floatx16;
typedef __attribute__((ext_vector_type(2))) float f32x2;
typedef __attribute__((ext_vector_type(4))) float f32x4;

__device__ __forceinline__ float wave_sum(float v) {
#pragma unroll
    for (int m = 1; m < 64; m <<= 1) v += __shfl_xor(v, m);
    return v;
}

// round-to-nearest-even fp32 -> bf16
__device__ __forceinline__ ushort f2bf(float f) {
    uint u = __float_as_uint(f);
    uint r = (u + 0x7fffu + ((u >> 16) & 1u)) >> 16;
    return (ushort)r;
}

// k_pre: split x (blocks 0..2047), qw (2048..2175), kw (2176..2303) into
// bf16 hi/lo planes. Each thread: one float4 -> ushort4 hi + ushort4 lo.
// Block 0 also zeroes the 32 stat words (k0 fused; k1 reads them only in the
// next dispatch, so no intra-kernel ordering is needed).
__global__ __launch_bounds__(256) void k_pre(const float* __restrict__ x,
                                             const float* __restrict__ qw,
                                             const float* __restrict__ kw,
                                             float* __restrict__ ws) {
    ushort* base = (ushort*)(ws + S_PL) + 4 * PLSZ;
    ushort* XH = base;
    ushort* XL = XH + 2097152;
    ushort* WH = XL + 2097152;
    ushort* WL = WH + 262144;
    const int bid = blockIdx.x;
    const int tid = threadIdx.x;
    if (bid == 0 && tid < 32) ws[S_STAT + tid] = 0.0f;
    const float* __restrict__ src;
    ushort *dh, *dl;
    int idx4;
    if (bid < 2048)      { src = x;  dh = XH;           dl = XL;           idx4 = bid * 256 + tid; }
    else if (bid < 2176) { src = qw; dh = WH;           dl = WL;           idx4 = (bid - 2048) * 256 + tid; }
    else                 { src = kw; dh = WH + 131072;  dl = WL + 131072;  idx4 = (bid - 2176) * 256 + tid; }
    const float4 v = *(const float4*)(src + (size_t)idx4 * 4);
    ushort4 hv, lv;
    {
        hv.x = f2bf(v.x); lv.x = f2bf(v.x - __uint_as_float(((uint)hv.x) << 16));
        hv.y = f2bf(v.y); lv.y = f2bf(v.y - __uint_as_float(((uint)hv.y) << 16));
        hv.z = f2bf(v.z); lv.z = f2bf(v.z - __uint_as_float(((uint)hv.z) << 16));
        hv.w = f2bf(v.w); lv.w = f2bf(v.w - __uint_as_float(((uint)hv.w) << 16));
    }
    *(ushort4*)(dh + (size_t)idx4 * 4) = hv;
    *(ushort4*)(dl + (size_t)idx4 * 4) = lv;
}

// K1 (MFMA): [8192 x 256] x [256 x 1024] -> q (cols 0..511) / k (cols 512..1023),
// split-bf16 3-term. Block = 128x128 tile, 4 waves (wave w: rows w&1, cols w>>1).
__global__ __launch_bounds__(256, 2) void k1_mfma(float* __restrict__ ws) {
    const ushort* base = (const ushort*)(ws + S_PL) + 4 * PLSZ;
    const ushort* __restrict__ XH = base;
    const ushort* __restrict__ XL = XH + 2097152;
    const ushort* __restrict__ WH = XL + 2097152;
    const ushort* __restrict__ WL = WH + 262144;
    const int t = threadIdx.x;
    const int l = t & 63;
    const int w = t >> 6;
    const int rw = w & 1, cw = w >> 1;
    const int row0 = blockIdx.x * 128 + rw * 64;   // n base of this wave
    const int col0 = blockIdx.y * 128 + cw * 64;   // j base of this wave (one head)
    const int lane31 = l & 31;
    const int kb8 = (l >> 5) * 8;

    floatx16 acc[2][2] = {};
#pragma unroll 4
    for (int kc = 0; kc < 256; kc += 16) {
        short8 ah[2], al[2], bh[2], bl[2];
#pragma unroll
        for (int rt = 0; rt < 2; ++rt) {
            const size_t o = (size_t)(row0 + rt * 32 + lane31) * 256 + kc + kb8;
            ah[rt] = *(const short8*)(XH + o);
            al[rt] = *(const short8*)(XL + o);
        }
#pragma unroll
        for (int ct = 0; ct < 2; ++ct) {
            const size_t o = (size_t)(col0 + ct * 32 + lane31) * 256 + kc + kb8;
            bh[ct] = *(const short8*)(WH + o);
            bl[ct] = *(const short8*)(WL + o);
        }
#pragma unroll
        for (int rt = 0; rt < 2; ++rt)
#pragma unroll
            for (int ct = 0; ct < 2; ++ct) {
                acc[rt][ct] = __builtin_amdgcn_mfma_f32_32x32x16_bf16(ah[rt], bh[ct], acc[rt][ct], 0, 0, 0);
                acc[rt][ct] = __builtin_amdgcn_mfma_f32_32x32x16_bf16(al[rt], bh[ct], acc[rt][ct], 0, 0, 0);
                acc[rt][ct] = __builtin_amdgcn_mfma_f32_32x32x16_bf16(ah[rt], bl[ct], acc[rt][ct], 0, 0, 0);
            }
    }

    const bool is_q = (col0 < 512);
    float* __restrict__ outp = ws + (is_q ? S_Q : S_K);
    const int cbase = col0 & 511;
    const int rsub = 4 * (l >> 5);
    float s1 = 0.f, s2 = 0.f;
#pragma unroll
    for (int rt = 0; rt < 2; ++rt)
#pragma unroll
        for (int ct = 0; ct < 2; ++ct)
#pragma unroll
            for (int e = 0; e < 16; ++e) {
                const int r = row0 + rt * 32 + rsub + (e & 3) + 8 * (e >> 2);
                const int c = cbase + ct * 32 + lane31;
                const float v = acc[rt][ct][e];
                outp[(size_t)r * 512 + c] = v;
                s1 += v; s2 += v * v;
            }
    s1 = wave_sum(s1);
    s2 = wave_sum(s2);
    if (l == 0) {
        const int head = (cbase >> 6) & 7;
        const int sb = (is_q ? 0 : 16) + head;
        atomicAdd(ws + S_STAT + sb, s1);
        atomicAdd(ws + S_STAT + sb + 8, s2);
    }
}

// K3 v2 (vectorized per G13): lane owns 4 consecutive d (16-B f32x4 load,
// ushort4 stores); a wave handles 4 n at once in 16-lane groups; the L2-norm
// reduce is 4 local squares + 4-level __shfl_xor tree (masks 1,2,4,8 stay
// within the group). Iterations/thread 16 -> 4.
__global__ __launch_bounds__(256) void k3_norm(const float* __restrict__ bnw,
                                               const float* __restrict__ bnb,
                                               float* __restrict__ ws) {
    const int t = threadIdx.x;
    const int w = t >> 6, l = t & 63;
    const int g = l >> 4, l16 = l & 15;
    const int nb = blockIdx.x;
    const int bh = blockIdx.y;
    const int b = bh >> 3, h = bh & 7;
    const int z = blockIdx.z;
    const float* __restrict__ in = ws + (z ? S_K : S_Q);
    const float* st = ws + S_STAT + (z ? 16 : 0);
    ushort* __restrict__ PH = (ushort*)(ws + S_PL) + (z ? 2 * PLSZ : 0) + (size_t)bh * 65536;
    ushort* __restrict__ PL = PH + PLSZ;
    const float inv_m = 1.0f / 524288.0f;
    const float mean  = st[h] * inv_m;
    const float var   = st[8 + h] * inv_m - mean * mean;
    const float alpha = rsqrtf(var + 1e-5f) * bnw[h];
    const float beta  = bnb[h] - mean * alpha;
    const float scale = z ? 0.0625f : 1.0f;   // fold 1/sqrt(256) into K

    const int d0 = l16 * 4;
#pragma unroll 1
    for (int i = 0; i < 4; ++i) {
        const int n = nb * 64 + w * 16 + i * 4 + g;
        const f32x4 vv = *(const f32x4*)&in[(size_t)(b * 1024 + n) * 512 + h * 64 + d0];
        float v0 = fmaf(vv.x, alpha, beta);
        float v1 = fmaf(vv.y, alpha, beta);
        float v2 = fmaf(vv.z, alpha, beta);
        float v3 = fmaf(vv.w, alpha, beta);
        float ss = v0 * v0 + v1 * v1 + v2 * v2 + v3 * v3;
        ss += __shfl_xor(ss, 1);
        ss += __shfl_xor(ss, 2);
        ss += __shfl_xor(ss, 4);
        ss += __shfl_xor(ss, 8);
        const float inv = scale / fmaxf(sqrtf(ss), 1e-12f);
        v0 *= inv; v1 *= inv; v2 *= inv; v3 *= inv;
        ushort4 hv, lv;
        hv.x = f2bf(v0); lv.x = f2bf(v0 - __uint_as_float(((uint)hv.x) << 16));
        hv.y = f2bf(v1); lv.y = f2bf(v1 - __uint_as_float(((uint)hv.y) << 16));
        hv.z = f2bf(v2); lv.z = f2bf(v2 - __uint_as_float(((uint)hv.z) << 16));
        hv.w = f2bf(v3); lv.w = f2bf(v3 - __uint_as_float(((uint)hv.w) << 16));
        const int idx = n * 64 + d0;
        *(ushort4*)&PH[idx] = hv;
        *(ushort4*)&PL[idx] = lv;
    }
}

// K4: write-locality block mapping (r7, confirmed): bid = bh*32 + j, bh slow;
// m0 = (j&7)*128 + (j>>3)*32 so the 4 same-XCD siblings own a contiguous
// 512-B m-strip per output row; plain stores so the XCD L2 aggregates dirty
// lines. Sparsemax: sum pass -> 5 monotone-secant evals -> exact-support pass.
__global__ __launch_bounds__(256, 3) void k4_attn(const float* __restrict__ ws,
                                                  float* __restrict__ out) {
    __shared__ float part[4][4][32];
    const int t = threadIdx.x;
    const int l = t & 63;
    const int w = t >> 6;
    const int bid = blockIdx.x;
    const int bh = bid >> 5;                    // 0..63 (slow)
    const int j  = bid & 31;                    // 0..31 (fast, co-resident siblings)
    const int m0 = ((j & 7) << 7) + ((j >> 3) << 5);  // XCD-contiguous m strips
    const int b = bh >> 3, h = bh & 7;
    const ushort* __restrict__ QH = (const ushort*)(ws + S_PL);
    const ushort* __restrict__ QL = QH + PLSZ;
    const ushort* __restrict__ KH = QH + 2 * PLSZ;
    const ushort* __restrict__ KL = QH + 3 * PLSZ;

    const int row = l & 31;
    const int kb8 = l >> 5;

    floatx16 acc[8] = {};

    const size_t koff = (size_t)(bh * 1024 + m0 + row) * 64 + kb8 * 8;
#pragma unroll
    for (int r = 0; r < 8; ++r) {
        const size_t qoff = (size_t)(bh * 1024 + w * 256 + r * 32 + row) * 64 + kb8 * 8;
#pragma unroll
        for (int ks = 0; ks < 4; ++ks) {
            short8 ah = *(const short8*)(QH + qoff + ks * 16);
            short8 al = *(const short8*)(QL + qoff + ks * 16);
            short8 kh = *(const short8*)(KH + koff + ks * 16);   // L1-hit reload
            short8 kl = *(const short8*)(KL + koff + ks * 16);
            acc[r] = __builtin_amdgcn_mfma_f32_32x32x16_bf16(ah, kh, acc[r], 0, 0, 0);
            acc[r] = __builtin_amdgcn_mfma_f32_32x32x16_bf16(al, kh, acc[r], 0, 0, 0);
            acc[r] = __builtin_amdgcn_mfma_f32_32x32x16_bf16(ah, kl, acc[r], 0, 0, 0);
        }
    }

    // ---- sparsemax per column m = m0 + (l&31) over n = 1024 ----
    const int col = row;

    // pass 0: column sum (packed)
    {
        f32x2 sv = {0.f, 0.f};
#pragma unroll
        for (int r = 0; r < 8; ++r)
#pragma unroll
            for (int p = 0; p < 8; ++p) {
                f32x2 z2 = { acc[r][2 * p], acc[r][2 * p + 1] };
                sv += z2;
            }
        float vsuml = sv.x + sv.y;
        vsuml += __shfl_xor(vsuml, 32);
        if (l < 32) part[2][w][col] = vsuml;
    }
    __syncthreads();
    const float vsum = part[2][0][col] + part[2][1][col]
                     + part[2][2][col] + part[2][3][col];

    float tcur = (vsum - 1.0f) * (1.0f / 1024.0f);   // tau0 <= tau*
    float tprev = tcur, sprev = 0.f;
#pragma unroll 1
    for (int it = 0; it < 5; ++it) {
        f32x2 s2v = {0.f, 0.f};
#pragma unroll
        for (int r = 0; r < 8; ++r) {
            f32x2 sr = {0.f, 0.f};
#pragma unroll
            for (int p = 0; p < 8; ++p) {
                f32x2 z2 = { acc[r][2 * p], acc[r][2 * p + 1] };
                f32x2 d = z2 - tcur;         // v_pk_add_f32
                d.x = fmaxf(d.x, 0.f);       // scalar v_max (no packed fp32 max)
                d.y = fmaxf(d.y, 0.f);
                sr += d;                     // v_pk_add_f32
            }
            s2v += sr;                       // 8 independent chains, tree-combined
        }
        float sl = s2v.x + s2v.y;
        sl += __shfl_xor(sl, 32);
        if (l < 32) part[it & 1][w][col] = sl;
        __syncthreads();   // double-buffered partials: one barrier per eval
        const float s = part[it & 1][0][col] + part[it & 1][1][col]
                      + part[it & 1][2][col] + part[it & 1][3][col];
        const float g = s - 1.0f;
        float step;
        if (it == 0) {
            step = g * (1.0f / 1024.0f);     // Newton with full-support slope
        } else {
            const float denom = sprev - s;   // >= 0 by monotonicity
            step = (denom > 1e-30f) ? g * (tcur - tprev) / denom : 0.f;
        }
        step = fmaxf(step, 0.f);             // keep tau <= tau* (monotone)
        tprev = tcur; sprev = s;
        tcur += step;
    }

    // exact-support pass: tau = (sum_{z>tcur} z - 1) / cnt
    float cntl = 0.f, ssml = 0.f;
#pragma unroll
    for (int r = 0; r < 8; ++r)
#pragma unroll
        for (int e = 0; e < 16; ++e) {
            const float zz = acc[r][e];
            if (zz > tcur) { cntl += 1.f; ssml += zz; }
        }
    cntl += __shfl_xor(cntl, 32);
    ssml += __shfl_xor(ssml, 32);
    if (l < 32) { part[2][w][col] = cntl; part[3][w][col] = ssml; }
    __syncthreads();
    const float cnt  = part[2][0][col] + part[2][1][col] + part[2][2][col] + part[2][3][col];
    const float ssum = part[3][0][col] + part[3][1][col] + part[3][2][col] + part[3][3][col];
    const float tau = (ssum - 1.0f) / cnt;

    float* __restrict__ ob = out + (size_t)b * 1024 * 8192 + h * 1024 + m0 + col;
    const int nbase = w * 256 + 4 * kb8;
#pragma unroll
    for (int r = 0; r < 8; ++r)
#pragma unroll
        for (int e = 0; e < 16; ++e) {
            const int n = nbase + r * 32 + (e & 3) + 8 * (e >> 2);
            ob[(size_t)n * 8192] = fmaxf(acc[r][e] - tau, 0.f);
        }
}

extern "C" void kernel_launch(void* const* d_in, const int* in_sizes, int n_in,
                              void* d_out, int out_size, void* d_ws, size_t ws_size,
                              hipStream_t stream) {
    (void)in_sizes; (void)n_in; (void)out_size; (void)ws_size;
    const float* x   = (const float*)d_in[0];
    const float* qw  = (const float*)d_in[1];
    const float* kw  = (const float*)d_in[2];
    const float* bnw = (const float*)d_in[3];
    const float* bnb = (const float*)d_in[4];
    float* ws  = (float*)d_ws;
    float* out = (float*)d_out;

    hipLaunchKernelGGL(k_pre, dim3(2304), dim3(256), 0, stream, x, qw, kw, ws);
    hipLaunchKernelGGL(k1_mfma, dim3(64, 8), dim3(256), 0, stream, ws);
    hipLaunchKernelGGL(k3_norm, dim3(16, 64, 2), dim3(256), 0, stream, bnw, bnb, ws);
    hipLaunchKernelGGL(k4_attn, dim3(2048), dim3(256), 0, stream, ws, out);
}